// Round 1
// baseline (94.903 us; speedup 1.0000x reference)
//
#include <hip/hip_runtime.h>

// Diagonal RNN scan: h_t = a_p * h_{t-1} + x_t,  a_p = 1 - relu(w_p), h_{-1}=0.
// Shapes: x (B=32, L=8192, P=128) fp32, w (P,) fp32, out (B,L,P) fp32.
// 3-pass chunked scan. A is constant over t, so inter-chunk combine factor is
// a^CHUNK (computed analytically) -- no product storage needed.

#define BB 32
#define LL 8192
#define PP 128
#define CHUNK 64
#define NCHUNK (LL / CHUNK)   // 128
#define CPB 8                 // chunks per block (one 32-lane group each)
#define GRID1 (BB * (NCHUNK / CPB))  // 512 blocks

// ---------------- Pass 1: per-chunk local scan, store chunk-final h ----------
__global__ __launch_bounds__(256) void pass1_chunk_last(
    const float* __restrict__ x, const float* __restrict__ w,
    float* __restrict__ carry /* [B][NCHUNK][P] */) {
  const int tid = threadIdx.x;
  const int g = tid >> 5;   // group 0..7 -> chunk
  const int l = tid & 31;   // lane in group -> float4 index over P
  const int bid = blockIdx.x;
  const int b = bid / (NCHUNK / CPB);
  const int cg = bid % (NCHUNK / CPB);
  const int c = cg * CPB + g;

  const float4 w4 = reinterpret_cast<const float4*>(w)[l];
  float4 a4;
  a4.x = 1.0f - fmaxf(w4.x, 0.0f);
  a4.y = 1.0f - fmaxf(w4.y, 0.0f);
  a4.z = 1.0f - fmaxf(w4.z, 0.0f);
  a4.w = 1.0f - fmaxf(w4.w, 0.0f);

  const float4* xv = reinterpret_cast<const float4*>(x) +
                     ((size_t)b * LL + (size_t)c * CHUNK) * (PP / 4) + l;
  float4 h = make_float4(0.f, 0.f, 0.f, 0.f);
#pragma unroll 8
  for (int t = 0; t < CHUNK; ++t) {
    const float4 v = xv[(size_t)t * (PP / 4)];
    h.x = fmaf(a4.x, h.x, v.x);
    h.y = fmaf(a4.y, h.y, v.y);
    h.z = fmaf(a4.z, h.z, v.z);
    h.w = fmaf(a4.w, h.w, v.w);
  }
  reinterpret_cast<float4*>(carry)[((size_t)b * NCHUNK + c) * (PP / 4) + l] = h;
}

// ---------------- Pass 2: scan carries across chunks (exclusive, in place) ---
__global__ __launch_bounds__(128) void pass2_carry_scan(
    const float* __restrict__ w, float* __restrict__ buf /* [B][NCHUNK][P] */) {
  const int p = threadIdx.x;
  const int b = blockIdx.x;
  const float a = 1.0f - fmaxf(w[p], 0.0f);
  float aC = a;
#pragma unroll
  for (int i = 0; i < 6; ++i) aC *= aC;  // a^64 == a^CHUNK
  float h = 0.f;
  float* base = buf + (size_t)b * NCHUNK * PP + p;
#pragma unroll 4
  for (int c = 0; c < NCHUNK; ++c) {
    const float last = base[(size_t)c * PP];
    base[(size_t)c * PP] = h;       // exclusive carry into chunk c
    h = fmaf(aC, h, last);
  }
}

// ---------------- Pass 3: recompute local scan seeded with carry, write out --
__global__ __launch_bounds__(256) void pass3_emit(
    const float* __restrict__ x, const float* __restrict__ w,
    const float* __restrict__ excl /* [B][NCHUNK][P] */,
    float* __restrict__ out) {
  const int tid = threadIdx.x;
  const int g = tid >> 5;
  const int l = tid & 31;
  const int bid = blockIdx.x;
  const int b = bid / (NCHUNK / CPB);
  const int cg = bid % (NCHUNK / CPB);
  const int c = cg * CPB + g;

  const float4 w4 = reinterpret_cast<const float4*>(w)[l];
  float4 a4;
  a4.x = 1.0f - fmaxf(w4.x, 0.0f);
  a4.y = 1.0f - fmaxf(w4.y, 0.0f);
  a4.z = 1.0f - fmaxf(w4.z, 0.0f);
  a4.w = 1.0f - fmaxf(w4.w, 0.0f);

  float4 h = reinterpret_cast<const float4*>(excl)[((size_t)b * NCHUNK + c) * (PP / 4) + l];

  const size_t off = ((size_t)b * LL + (size_t)c * CHUNK) * (PP / 4) + l;
  const float4* xv = reinterpret_cast<const float4*>(x) + off;
  float4* ov = reinterpret_cast<float4*>(out) + off;
#pragma unroll 8
  for (int t = 0; t < CHUNK; ++t) {
    const float4 v = xv[(size_t)t * (PP / 4)];
    h.x = fmaf(a4.x, h.x, v.x);
    h.y = fmaf(a4.y, h.y, v.y);
    h.z = fmaf(a4.z, h.z, v.z);
    h.w = fmaf(a4.w, h.w, v.w);
    ov[(size_t)t * (PP / 4)] = h;
  }
}

extern "C" void kernel_launch(void* const* d_in, const int* in_sizes, int n_in,
                              void* d_out, int out_size, void* d_ws, size_t ws_size,
                              hipStream_t stream) {
  const float* x = (const float*)d_in[0];
  const float* w = (const float*)d_in[1];
  float* out = (float*)d_out;
  float* buf = (float*)d_ws;  // needs B*NCHUNK*P*4 = 2 MiB

  pass1_chunk_last<<<GRID1, 256, 0, stream>>>(x, w, buf);
  pass2_carry_scan<<<BB, 128, 0, stream>>>(w, buf);
  pass3_emit<<<GRID1, 256, 0, stream>>>(x, w, buf, out);
}

// Round 3
// 84.732 us; speedup vs baseline: 1.1200x; 1.1200x over previous
//
#include <hip/hip_runtime.h>

// Diagonal RNN scan: h_t = a_p * h_{t-1} + x_t,  a_p = 1 - relu(w_p), h_{-1}=0.
// Shapes: x (B=32, L=8192, P=128) fp32, w (P,) fp32, out (B,L,P) fp32.
// 3-pass chunked scan; A constant over t so inter-chunk factor is a^CHUNK.
// R3: native ext_vector float4 (nontemporal builtins reject HIP_vector_type).

typedef float f4 __attribute__((ext_vector_type(4)));

#define BB 32
#define LL 8192
#define PP 128
#define CHUNK 32
#define NCHUNK (LL / CHUNK)          // 256
#define CPB 8                        // chunks per block (one 32-lane group each)
#define GRID1 (BB * (NCHUNK / CPB))  // 1024 blocks

// ---------------- Pass 1: per-chunk local scan, store chunk-final h ----------
__global__ __launch_bounds__(256) void pass1_chunk_last(
    const float* __restrict__ x, const float* __restrict__ w,
    float* __restrict__ carry /* [B][NCHUNK][P] */) {
  const int tid = threadIdx.x;
  const int g = tid >> 5;   // group 0..7 -> chunk
  const int l = tid & 31;   // lane in group -> float4 index over P
  const int bid = blockIdx.x;
  const int b = bid / (NCHUNK / CPB);
  const int cg = bid % (NCHUNK / CPB);
  const int c = cg * CPB + g;

  const f4 w4 = reinterpret_cast<const f4*>(w)[l];
  f4 a4;
  a4.x = 1.0f - fmaxf(w4.x, 0.0f);
  a4.y = 1.0f - fmaxf(w4.y, 0.0f);
  a4.z = 1.0f - fmaxf(w4.z, 0.0f);
  a4.w = 1.0f - fmaxf(w4.w, 0.0f);

  const f4* xv = reinterpret_cast<const f4*>(x) +
                 ((size_t)b * LL + (size_t)c * CHUNK) * (PP / 4) + l;
  f4 h = (f4)(0.0f);
#pragma unroll 8
  for (int t = 0; t < CHUNK; ++t) {
    const f4 v = xv[(size_t)t * (PP / 4)];
    h.x = fmaf(a4.x, h.x, v.x);
    h.y = fmaf(a4.y, h.y, v.y);
    h.z = fmaf(a4.z, h.z, v.z);
    h.w = fmaf(a4.w, h.w, v.w);
  }
  reinterpret_cast<f4*>(carry)[((size_t)b * NCHUNK + c) * (PP / 4) + l] = h;
}

// ------- Pass 2: scan carries across chunks, write EXCLUSIVE prefix ---------
__global__ __launch_bounds__(64) void pass2_carry_scan(
    const float* __restrict__ w,
    const float* __restrict__ carry /* [B][NCHUNK][P] */,
    float* __restrict__ excl /* [B][NCHUNK][P] */) {
  const int gid = blockIdx.x * 64 + threadIdx.x;  // 0..4095 -> (b, p)
  const int b = gid >> 7;
  const int p = gid & 127;
  const float a = 1.0f - fmaxf(w[p], 0.0f);
  float aC = a;
#pragma unroll
  for (int i = 0; i < 5; ++i) aC *= aC;  // a^32 == a^CHUNK
  float h = 0.f;
  const float* in = carry + (size_t)b * NCHUNK * PP + p;
  float* outp = excl + (size_t)b * NCHUNK * PP + p;
#pragma unroll 8
  for (int c = 0; c < NCHUNK; ++c) {
    const float last = in[(size_t)c * PP];
    outp[(size_t)c * PP] = h;  // exclusive carry into chunk c
    h = fmaf(aC, h, last);
  }
}

// ---------------- Pass 3: recompute local scan seeded with carry, write out --
__global__ __launch_bounds__(256) void pass3_emit(
    const float* __restrict__ x, const float* __restrict__ w,
    const float* __restrict__ excl /* [B][NCHUNK][P] */,
    float* __restrict__ out) {
  const int tid = threadIdx.x;
  const int g = tid >> 5;
  const int l = tid & 31;
  const int bid = blockIdx.x;
  const int b = bid / (NCHUNK / CPB);
  const int cg = bid % (NCHUNK / CPB);
  const int c = cg * CPB + g;

  const f4 w4 = reinterpret_cast<const f4*>(w)[l];
  f4 a4;
  a4.x = 1.0f - fmaxf(w4.x, 0.0f);
  a4.y = 1.0f - fmaxf(w4.y, 0.0f);
  a4.z = 1.0f - fmaxf(w4.z, 0.0f);
  a4.w = 1.0f - fmaxf(w4.w, 0.0f);

  f4 h = reinterpret_cast<const f4*>(excl)[((size_t)b * NCHUNK + c) * (PP / 4) + l];

  const size_t off = ((size_t)b * LL + (size_t)c * CHUNK) * (PP / 4) + l;
  const f4* xv = reinterpret_cast<const f4*>(x) + off;
  f4* ov = reinterpret_cast<f4*>(out) + off;
#pragma unroll 8
  for (int t = 0; t < CHUNK; ++t) {
    const f4 v = __builtin_nontemporal_load(&xv[(size_t)t * (PP / 4)]);
    h.x = fmaf(a4.x, h.x, v.x);
    h.y = fmaf(a4.y, h.y, v.y);
    h.z = fmaf(a4.z, h.z, v.z);
    h.w = fmaf(a4.w, h.w, v.w);
    __builtin_nontemporal_store(h, &ov[(size_t)t * (PP / 4)]);
  }
}

extern "C" void kernel_launch(void* const* d_in, const int* in_sizes, int n_in,
                              void* d_out, int out_size, void* d_ws, size_t ws_size,
                              hipStream_t stream) {
  const float* x = (const float*)d_in[0];
  const float* w = (const float*)d_in[1];
  float* out = (float*)d_out;
  float* carry = (float*)d_ws;                       // 4 MiB
  float* excl = carry + (size_t)BB * NCHUNK * PP;    // 4 MiB

  pass1_chunk_last<<<GRID1, 256, 0, stream>>>(x, w, carry);
  pass2_carry_scan<<<BB * PP / 64, 64, 0, stream>>>(w, carry, excl);
  pass3_emit<<<GRID1, 256, 0, stream>>>(x, w, excl, out);
}

// Round 4
// 82.656 us; speedup vs baseline: 1.1482x; 1.0251x over previous
//
#include <hip/hip_runtime.h>

// Diagonal RNN scan: h_t = a_p * h_{t-1} + x_t,  a_p = 1 - relu(w_p), h_{-1}=0.
// x (B=32, L=8192, P=128) fp32, w (P,) fp32, out (B,L,P) fp32.
// R4: 2-kernel redundant-lookback. k1 writes per-chunk finals; k2 recomputes
// its own exclusive carry from the finals (A const => combine factor a^CHUNK),
// then emits. No third pass, no spin, no global barrier.

typedef float f4 __attribute__((ext_vector_type(4)));

#define BB 32
#define LL 8192
#define PP 128
#define CHUNK 32
#define NCHUNK (LL / CHUNK)          // 256
#define CPB 8                        // chunks per block (one 32-lane group each)
#define BPR (NCHUNK / CPB)           // 32 blocks per batch-row
#define GRID1 (BB * BPR)             // 1024 blocks

// ---------------- k1: per-chunk local scan, store chunk-final h --------------
__global__ __launch_bounds__(256) void k1_chunk_finals(
    const float* __restrict__ x, const float* __restrict__ w,
    float* __restrict__ finals /* [B][NCHUNK][P] */) {
  const int tid = threadIdx.x;
  const int g = tid >> 5;   // group 0..7 -> chunk
  const int l = tid & 31;   // lane -> float4 index over P
  const int b = blockIdx.x / BPR;
  const int cg = blockIdx.x % BPR;
  const int c = cg * CPB + g;

  const f4 w4 = reinterpret_cast<const f4*>(w)[l];
  f4 a4;
  a4.x = 1.0f - fmaxf(w4.x, 0.0f);
  a4.y = 1.0f - fmaxf(w4.y, 0.0f);
  a4.z = 1.0f - fmaxf(w4.z, 0.0f);
  a4.w = 1.0f - fmaxf(w4.w, 0.0f);

  const f4* xv = reinterpret_cast<const f4*>(x) +
                 ((size_t)b * LL + (size_t)c * CHUNK) * (PP / 4) + l;
  f4 h = (f4)(0.0f);
#pragma unroll 8
  for (int t = 0; t < CHUNK; ++t) {
    const f4 v = xv[(size_t)t * (PP / 4)];
    h.x = fmaf(a4.x, h.x, v.x);
    h.y = fmaf(a4.y, h.y, v.y);
    h.z = fmaf(a4.z, h.z, v.z);
    h.w = fmaf(a4.w, h.w, v.w);
  }
  reinterpret_cast<f4*>(finals)[((size_t)b * NCHUNK + c) * (PP / 4) + l] = h;
}

// ------- k2: redundant lookback over finals + seeded emit --------------------
__global__ __launch_bounds__(256) void k2_lookback_emit(
    const float* __restrict__ x, const float* __restrict__ w,
    const float* __restrict__ finals /* [B][NCHUNK][P] */,
    float* __restrict__ out) {
  const int tid = threadIdx.x;
  const int b = blockIdx.x / BPR;
  const int cg = blockIdx.x % BPR;
  const int C0 = cg * CPB;

  __shared__ float sexcl[CPB][PP];  // 4 KiB: exclusive seed per chunk

  if (tid < PP) {
    const int p = tid;
    const float a = 1.0f - fmaxf(w[p], 0.0f);
    float aC = a;
#pragma unroll
    for (int i = 0; i < 5; ++i) aC *= aC;  // a^32 == a^CHUNK
    float h = 0.f;
    const float* fp = finals + (size_t)b * NCHUNK * PP + p;
#pragma unroll 8
    for (int c = 0; c < C0; ++c) h = fmaf(aC, h, fp[(size_t)c * PP]);
    // h is now exclusive carry for chunk C0; extend over our 8 chunks
#pragma unroll
    for (int g = 0; g < CPB; ++g) {
      sexcl[g][p] = h;
      h = fmaf(aC, h, fp[(size_t)(C0 + g) * PP]);
    }
  }
  __syncthreads();

  const int g = tid >> 5;
  const int l = tid & 31;
  const int c = C0 + g;

  const f4 w4 = reinterpret_cast<const f4*>(w)[l];
  f4 a4;
  a4.x = 1.0f - fmaxf(w4.x, 0.0f);
  a4.y = 1.0f - fmaxf(w4.y, 0.0f);
  a4.z = 1.0f - fmaxf(w4.z, 0.0f);
  a4.w = 1.0f - fmaxf(w4.w, 0.0f);

  f4 h = reinterpret_cast<const f4*>(&sexcl[g][0])[l];

  const size_t off = ((size_t)b * LL + (size_t)c * CHUNK) * (PP / 4) + l;
  const f4* xv = reinterpret_cast<const f4*>(x) + off;
  f4* ov = reinterpret_cast<f4*>(out) + off;
#pragma unroll 8
  for (int t = 0; t < CHUNK; ++t) {
    const f4 v = __builtin_nontemporal_load(&xv[(size_t)t * (PP / 4)]);
    h.x = fmaf(a4.x, h.x, v.x);
    h.y = fmaf(a4.y, h.y, v.y);
    h.z = fmaf(a4.z, h.z, v.z);
    h.w = fmaf(a4.w, h.w, v.w);
    __builtin_nontemporal_store(h, &ov[(size_t)t * (PP / 4)]);
  }
}

extern "C" void kernel_launch(void* const* d_in, const int* in_sizes, int n_in,
                              void* d_out, int out_size, void* d_ws, size_t ws_size,
                              hipStream_t stream) {
  const float* x = (const float*)d_in[0];
  const float* w = (const float*)d_in[1];
  float* out = (float*)d_out;
  float* finals = (float*)d_ws;  // 4 MiB

  k1_chunk_finals<<<GRID1, 256, 0, stream>>>(x, w, finals);
  k2_lookback_emit<<<GRID1, 256, 0, stream>>>(x, w, finals, out);
}

// Round 5
// 66.866 us; speedup vs baseline: 1.4193x; 1.2361x over previous
//
#include <hip/hip_runtime.h>

// Diagonal RNN scan: h_t = a_p * h_{t-1} + x_t,  a_p = 1 - relu(w_p), h_{-1}=0.
// x (B=32, L=8192, P=128) fp32, w (P,) fp32, out (B,L,P) fp32.
// R5: k1 publishes per-BLOCK finals only (1 MB). k2 holds its x-block in
// registers, recomputes chunk finals locally, does a batched lookback over
// predecessor block-finals, then emits from registers. Normal (cacheable)
// loads for x in k2 (L3-resident from k1); nt stores for out.

typedef float f4 __attribute__((ext_vector_type(4)));

#define BB 32
#define LL 8192
#define PP 128
#define CHUNK 16                 // timesteps per 32-lane group
#define GPB 8                    // groups per block
#define BSTEPS (CHUNK * GPB)     // 128 timesteps per block
#define BPR (LL / BSTEPS)        // 64 blocks per batch-row
#define GRID (BB * BPR)          // 2048 blocks

__device__ __forceinline__ f4 load_a4(const float* __restrict__ w, int l) {
  const f4 w4 = reinterpret_cast<const f4*>(w)[l];
  f4 a4;
  a4.x = 1.0f - fmaxf(w4.x, 0.0f);
  a4.y = 1.0f - fmaxf(w4.y, 0.0f);
  a4.z = 1.0f - fmaxf(w4.z, 0.0f);
  a4.w = 1.0f - fmaxf(w4.w, 0.0f);
  return a4;
}

// ---------------- k1: per-block final only ----------------------------------
__global__ __launch_bounds__(256) void k1_block_finals(
    const float* __restrict__ x, const float* __restrict__ w,
    float* __restrict__ bfin /* [B][BPR][P] */) {
  const int tid = threadIdx.x;
  const int g = tid >> 5;
  const int l = tid & 31;
  const int b = blockIdx.x / BPR;
  const int cg = blockIdx.x % BPR;
  const int c = cg * GPB + g;

  const f4 a4 = load_a4(w, l);

  const f4* xv = reinterpret_cast<const f4*>(x) +
                 ((size_t)b * LL + (size_t)c * CHUNK) * (PP / 4) + l;
  f4 h = (f4)(0.0f);
#pragma unroll
  for (int t = 0; t < CHUNK; ++t) {
    const f4 v = xv[(size_t)t * (PP / 4)];
    h.x = fmaf(a4.x, h.x, v.x);
    h.y = fmaf(a4.y, h.y, v.y);
    h.z = fmaf(a4.z, h.z, v.z);
    h.w = fmaf(a4.w, h.w, v.w);
  }

  __shared__ float sf[GPB][PP];
  reinterpret_cast<f4*>(&sf[g][0])[l] = h;
  __syncthreads();

  if (tid < PP) {
    const int p = tid;
    const float a = 1.0f - fmaxf(w[p], 0.0f);
    float a16 = a;
#pragma unroll
    for (int i = 0; i < 4; ++i) a16 *= a16;  // a^16
    float bf = 0.f;
#pragma unroll
    for (int g2 = 0; g2 < GPB; ++g2) bf = fmaf(a16, bf, sf[g2][p]);
    bfin[((size_t)b * BPR + cg) * PP + p] = bf;
  }
}

// ---------------- k2: reg-resident block scan + lookback + emit -------------
__global__ __launch_bounds__(256) void k2_scan_emit(
    const float* __restrict__ x, const float* __restrict__ w,
    const float* __restrict__ bfin /* [B][BPR][P] */,
    float* __restrict__ out) {
  const int tid = threadIdx.x;
  const int g = tid >> 5;
  const int l = tid & 31;
  const int b = blockIdx.x / BPR;
  const int cg = blockIdx.x % BPR;
  const int c = cg * GPB + g;

  const f4 a4 = load_a4(w, l);

  const size_t off = ((size_t)b * LL + (size_t)c * CHUNK) * (PP / 4) + l;
  const f4* xv = reinterpret_cast<const f4*>(x) + off;

  // Phase 1: load chunk into registers, compute chunk-final.
  f4 xr[CHUNK];
#pragma unroll
  for (int t = 0; t < CHUNK; ++t) xr[t] = xv[(size_t)t * (PP / 4)];

  f4 h = (f4)(0.0f);
#pragma unroll
  for (int t = 0; t < CHUNK; ++t) {
    h.x = fmaf(a4.x, h.x, xr[t].x);
    h.y = fmaf(a4.y, h.y, xr[t].y);
    h.z = fmaf(a4.z, h.z, xr[t].z);
    h.w = fmaf(a4.w, h.w, xr[t].w);
  }

  __shared__ float sf[GPB][PP];
  __shared__ float seed[GPB][PP];
  reinterpret_cast<f4*>(&sf[g][0])[l] = h;
  __syncthreads();

  // Phase 2: lookback over predecessor block-finals + intra-block seeds.
  if (tid < PP) {
    const int p = tid;
    const float a = 1.0f - fmaxf(w[p], 0.0f);
    float a16 = a;
#pragma unroll
    for (int i = 0; i < 4; ++i) a16 *= a16;  // a^16
    float a128 = a16;
#pragma unroll
    for (int i = 0; i < 3; ++i) a128 *= a128;  // a^128

    float hh = 0.f;
    const float* bp = bfin + (size_t)b * BPR * PP + p;
    int j = 0;
    for (; j + 8 <= cg; j += 8) {  // batch loads to pipeline L2 latency
      const float v0 = bp[(size_t)(j + 0) * PP];
      const float v1 = bp[(size_t)(j + 1) * PP];
      const float v2 = bp[(size_t)(j + 2) * PP];
      const float v3 = bp[(size_t)(j + 3) * PP];
      const float v4 = bp[(size_t)(j + 4) * PP];
      const float v5 = bp[(size_t)(j + 5) * PP];
      const float v6 = bp[(size_t)(j + 6) * PP];
      const float v7 = bp[(size_t)(j + 7) * PP];
      hh = fmaf(a128, hh, v0);
      hh = fmaf(a128, hh, v1);
      hh = fmaf(a128, hh, v2);
      hh = fmaf(a128, hh, v3);
      hh = fmaf(a128, hh, v4);
      hh = fmaf(a128, hh, v5);
      hh = fmaf(a128, hh, v6);
      hh = fmaf(a128, hh, v7);
    }
    for (; j < cg; ++j) hh = fmaf(a128, hh, bp[(size_t)j * PP]);

#pragma unroll
    for (int g2 = 0; g2 < GPB; ++g2) {
      seed[g2][p] = hh;
      hh = fmaf(a16, hh, sf[g2][p]);
    }
  }
  __syncthreads();

  // Phase 3: emit from registers, seeded.
  h = reinterpret_cast<const f4*>(&seed[g][0])[l];
  f4* ov = reinterpret_cast<f4*>(out) + off;
#pragma unroll
  for (int t = 0; t < CHUNK; ++t) {
    h.x = fmaf(a4.x, h.x, xr[t].x);
    h.y = fmaf(a4.y, h.y, xr[t].y);
    h.z = fmaf(a4.z, h.z, xr[t].z);
    h.w = fmaf(a4.w, h.w, xr[t].w);
    __builtin_nontemporal_store(h, &ov[(size_t)t * (PP / 4)]);
  }
}

extern "C" void kernel_launch(void* const* d_in, const int* in_sizes, int n_in,
                              void* d_out, int out_size, void* d_ws, size_t ws_size,
                              hipStream_t stream) {
  const float* x = (const float*)d_in[0];
  const float* w = (const float*)d_in[1];
  float* out = (float*)d_out;
  float* bfin = (float*)d_ws;  // 1 MiB

  k1_block_finals<<<GRID, 256, 0, stream>>>(x, w, bfin);
  k2_scan_emit<<<GRID, 256, 0, stream>>>(x, w, bfin, out);
}